// Round 15
// baseline (419.453 us; speedup 1.0000x reference)
//
#include <hip/hip_runtime.h>

namespace {

constexpr int NB_  = 2;
constexpr int TC_  = 1024;
constexpr int TP_  = 512;
constexpr int TT_  = 1536;   // TC + TP
constexpr int D_   = 128;
constexpr int H_   = 8;
constexpr int DK_  = 16;
constexpr int DFF_ = 512;
constexpr int L_   = 2;
constexpr int HOR_ = 96;
constexpr int NQ_  = 3;

constexpr int SCP_ = TT_ + 8;   // ushort stride per head row (even → dword-tiled)

typedef _Float16 h2 __attribute__((ext_vector_type(2)));

// ---- output float offsets (return order: out, v_cond, v_pred, logs) ----
constexpr int OFF_OUT  = 0;
constexpr int OFF_VC   = NB_ * NQ_ * HOR_;            // 576
constexpr int OFF_VP   = OFF_VC + NB_ * TC_ * 8;      // 16960
constexpr int OFF_LOGS = OFF_VP + NB_ * TP_ * 4;      // 21056

// ---- workspace float offsets ----
constexpr int WS_XA  = 0;
constexpr int WS_XB  = WS_XA  + NB_ * TT_ * D_;       // 393216
constexpr int WS_Q16 = WS_XB  + NB_ * TT_ * D_;       // f16, half-sized
constexpr int WS_K16 = WS_Q16 + NB_ * TT_ * D_ / 2;
constexpr int WS_VC  = WS_K16 + NB_ * TT_ * D_ / 2;
constexpr int WS_WVC = WS_VC  + NB_ * TT_ * DK_;      // 2 layers x 2048
constexpr int WS_BVC = WS_WVC + L_ * D_ * DK_;        // 2 layers x 16

__device__ inline float dot2f(h2 a, h2 b, float c) {
#if __has_builtin(__builtin_amdgcn_fdot2)
    return __builtin_amdgcn_fdot2(a, b, c, false);
#else
    return c + (float)a[0] * (float)b[0] + (float)a[1] * (float)b[1];
#endif
}

__device__ inline unsigned pack2h(float a, float b) {   // 1 inst: v_cvt_pkrtz
#if __has_builtin(__builtin_amdgcn_cvt_pkrtz)
    return __builtin_bit_cast(unsigned, __builtin_amdgcn_cvt_pkrtz(a, b));
#else
    h2 p; p[0] = (_Float16)a; p[1] = (_Float16)b;
    return __builtin_bit_cast(unsigned, p);
#endif
}

// =======================================================================
// Wv head-mean prep (tiny separate launch so wvc/bvc are ready before
// pre_kernel's fused QKV — no intra-kernel block-ordering assumption).
// =======================================================================
__global__ __launch_bounds__(128) void prep_wvc_kernel(
    const float* __restrict__ Wv, const float* __restrict__ bv,
    float* __restrict__ wvc, float* __restrict__ bvc)
{
    const int l = blockIdx.x;
    const float* W  = Wv + (long)l * D_ * D_;
    const float* bb = bv + l * D_;
    float* wv = wvc + l * D_ * DK_;
    float* bo = bvc + l * DK_;
    const int tid = threadIdx.x;
    for (int idx = tid; idx < D_ * DK_; idx += 128) {
        const int i = idx >> 4, dk = idx & 15;
        float s = 0.f;
        #pragma unroll
        for (int hh = 0; hh < H_; ++hh) s += W[i * D_ + hh * DK_ + dk];
        wv[idx] = s * 0.125f;
    }
    if (tid < DK_) {
        float s = 0.f;
        #pragma unroll
        for (int hh = 0; hh < H_; ++hh) s += bb[hh * DK_ + tid];
        bo[tid] = s * 0.125f;
    }
}

// =======================================================================
// Selector + fused layer-0 QKV, 256 threads per (b, t).
// =======================================================================
template <int NV>
__device__ inline void selector_qkv_body(
    const float* __restrict__ x, const float* __restrict__ cw,
    const float* __restrict__ cb, const float* __restrict__ sw,
    const float* __restrict__ sb, float* __restrict__ vout,
    float* __restrict__ xout, int Tsel, int row_off, int blk,
    const float* __restrict__ Wq, const float* __restrict__ bq,
    const float* __restrict__ Wk, const float* __restrict__ bk,
    const float* __restrict__ wvc, const float* __restrict__ bvc,
    _Float16* __restrict__ q16, _Float16* __restrict__ k16,
    float* __restrict__ vc)
{
    const int b = blk / Tsel;
    const int t = blk - b * Tsel;
    const int tid = threadIdx.x;         // 0..255
    const int d = tid & 127;
    const int hi = tid >> 7;             // wave-uniform
    const int lane = tid & 63, wave = tid >> 6;

    __shared__ float wsum[4][NV];
    __shared__ float wls[NV];
    __shared__ float xr[D_];
    __shared__ float vred[DK_][8];

    float xw[3 * NV];
    #pragma unroll
    for (int kk = 0; kk < 3; ++kk) {
        const int ts = t + kk - 2;
        #pragma unroll
        for (int v = 0; v < NV; ++v)
            xw[kk * NV + v] = (ts >= 0) ? x[((long)b * Tsel + ts) * NV + v] : 0.0f;
    }

    float ls[NV];
    #pragma unroll
    for (int v = 0; v < NV; ++v) {
        const float* cwp = cw + ((long)(v * D_ + d)) * 3;
        float a = cb[v * D_ + d];
        a = fmaf(xw[0 * NV + v], cwp[0], a);
        a = fmaf(xw[1 * NV + v], cwp[1], a);
        a = fmaf(xw[2 * NV + v], cwp[2], a);
        ls[v] = a;
    }

    {
        const float swd = sw[d];
        float p[NV];
        #pragma unroll
        for (int v = 0; v < NV; ++v) p[v] = ls[v] * swd;
        #pragma unroll
        for (int off = 32; off; off >>= 1) {
            #pragma unroll
            for (int v = 0; v < NV; ++v) p[v] += __shfl_xor(p[v], off);
        }
        if (lane == 0) {
            #pragma unroll
            for (int v = 0; v < NV; ++v) wsum[wave][v] = p[v];
        }
    }
    __syncthreads();

    if (tid == 0) {   // waves 2,3 hold duplicates; use waves 0,1 only
        float u[NV];
        float m = -1e30f;
        #pragma unroll
        for (int v = 0; v < NV; ++v) {
            float s = wsum[0][v] + wsum[1][v] + sb[0];
            s = fminf(fmaxf(s, -10.0f), 10.0f);
            u[v] = 0.5f * s;
            m = fmaxf(m, u[v]);
        }
        float tau = m - 1.0f;
        for (int it = 0; it < 12; ++it) {
            float S1 = 0.f, S2 = 0.f;
            #pragma unroll
            for (int v = 0; v < NV; ++v) {
                float dd = fmaxf(u[v] - tau, 0.f);
                S1 += dd; S2 = fmaf(dd, dd, S2);
            }
            tau += (S2 - 1.0f) / (2.0f * S1);
        }
        {
            float S1 = 0.f, S2 = 0.f, K = 0.f;
            #pragma unroll
            for (int v = 0; v < NV; ++v) {
                if (u[v] > tau) { S1 += u[v]; S2 = fmaf(u[v], u[v], S2); K += 1.f; }
            }
            const float mean = S1 / K;
            const float arg  = fmaxf(fmaf(mean, mean, -(S2 - 1.0f) / K), 0.f);
            tau = mean - sqrtf(arg);
        }
        #pragma unroll
        for (int v = 0; v < NV; ++v) {
            float dd = fmaxf(u[v] - tau, 0.f);
            wls[v] = dd * dd;
        }
    }
    __syncthreads();

    float acc = 0.f;
    #pragma unroll
    for (int v = 0; v < NV; ++v) acc = fmaf(ls[v], wls[v], acc);
    const long row = (long)b * TT_ + row_off + t;
    if (hi == 0) {
        xout[row * D_ + d] = acc;
        xr[d] = acc;
    }
    if (tid < NV) vout[((long)b * Tsel + t) * NV + tid] = wls[tid];
    __syncthreads();

    // ---- fused layer-0 QKV: half-block q, half-block k ----
    {
        const float* __restrict__ W = hi ? Wk : Wq;
        float a = hi ? bk[d] : bq[d];
        for (int i = 0; i < D_; ++i) a = fmaf(xr[i], W[i * D_ + d], a);
        _Float16* __restrict__ dst = hi ? k16 : q16;
        dst[row * D_ + d] = (_Float16)a;
    }

    if (tid < 128) {
        const int dk = tid & 15, ch = tid >> 4;
        float p = 0.f;
        #pragma unroll
        for (int i = 0; i < 16; ++i)
            p = fmaf(xr[ch * 16 + i], wvc[(ch * 16 + i) * DK_ + dk], p);
        vred[dk][ch] = p;
    }
    __syncthreads();
    if (tid < DK_) {
        float s = bvc[tid];
        #pragma unroll
        for (int ch = 0; ch < 8; ++ch) s += vred[tid][ch];
        vc[row * DK_ + tid] = s;
    }
}

__global__ __launch_bounds__(256) void pre_kernel(
    const float* __restrict__ x_cond, const float* __restrict__ cw_c,
    const float* __restrict__ cb_c, const float* __restrict__ sw_c,
    const float* __restrict__ sb_c,
    const float* __restrict__ x_pred, const float* __restrict__ cw_p,
    const float* __restrict__ cb_p, const float* __restrict__ sw_p,
    const float* __restrict__ sb_p,
    float* __restrict__ vc_out, float* __restrict__ vp_out,
    float* __restrict__ xout,
    const float* __restrict__ Wq, const float* __restrict__ bq,
    const float* __restrict__ Wk, const float* __restrict__ bk,
    const float* __restrict__ wvc, const float* __restrict__ bvc,
    _Float16* __restrict__ q16, _Float16* __restrict__ k16,
    float* __restrict__ vc)
{
    const int blk = blockIdx.x;
    if (blk < NB_ * TC_) {
        selector_qkv_body<8>(x_cond, cw_c, cb_c, sw_c, sb_c, vc_out, xout,
                             TC_, 0, blk, Wq, bq, Wk, bk, wvc, bvc,
                             q16, k16, vc);
    } else {
        selector_qkv_body<4>(x_pred, cw_p, cb_p, sw_p, sb_p, vp_out, xout,
                             TP_, TC_, blk - NB_ * TC_,
                             Wq, bq, Wk, bk, wvc, bvc, q16, k16, vc);
    }
}

// =======================================================================
// entmax15 tau for NE register-resident elements per lane (wave-wide row).
// Fixed 7 from-below Newton iterations + exact closed-form tau.
// =======================================================================
template <int NE>
__device__ inline float entmax_tau(const float* __restrict__ v, int lane)
{
    float m = -1e30f;
    #pragma unroll
    for (int j = 0; j < NE; ++j) m = fmaxf(m, v[j]);
    #pragma unroll
    for (int off = 32; off; off >>= 1) m = fmaxf(m, __shfl_xor(m, off));

    float tau = m - 1.0f;   // f(tau0) >= 0
    #pragma unroll
    for (int it = 0; it < 7; ++it) {
        float S1 = 0.f, S2 = 0.f;
        #pragma unroll
        for (int j = 0; j < NE; ++j) {
            const float d0 = fmaxf(v[j] - tau, 0.f);
            S1 += d0; S2 = fmaf(d0, d0, S2);
        }
        #pragma unroll
        for (int off = 32; off; off >>= 1) {
            S1 += __shfl_xor(S1, off);
            S2 += __shfl_xor(S2, off);
        }
        tau += (S2 - 1.0f) / (2.0f * S1);
    }
    {
        float S1 = 0.f, S2 = 0.f, K = 0.f;
        #pragma unroll
        for (int j = 0; j < NE; ++j) {
            if (v[j] > tau) { S1 += v[j]; S2 = fmaf(v[j], v[j], S2); K += 1.f; }
        }
        #pragma unroll
        for (int off = 32; off; off >>= 1) {
            S1 += __shfl_xor(S1, off);
            S2 += __shfl_xor(S2, off);
            K  += __shfl_xor(K,  off);
        }
        const float mean = S1 / K;
        const float arg  = fmaxf(fmaf(mean, mean, -(S2 - 1.0f) / K), 0.f);
        tau = mean - sqrtf(arg);
    }
    return tau;
}

// =======================================================================
// One head: compute scores DIRECTLY into Newton register layout (lane l
// owns s = 128j+2l, 128j+2l+1) via global K loads + fdot2 — no LDS
// round-trip, no score-phase barrier. Then Newton + f16 writeback to LDS
// (only what w_avg reads; masked slots pack to 0; slots >= NJ never read).
// =======================================================================
template <int NJ>
__device__ inline void head_score_newton(
    const _Float16* __restrict__ kb,   // k16 + bbase*D_
    const h2* __restrict__ qv,         // 8 x h2 (this head's q)
    unsigned short* __restrict__ srow, // scb + head*SCP_
    int lane, int t, int hoff)         // hoff: head*DK_ element offset
{
    float v[2 * NJ];
    #pragma unroll
    for (int j = 0; j < NJ; ++j) {
        const int s0 = 128 * j + 2 * lane;
        float d0 = -1e30f, d1 = -1e30f;
        if (s0 <= t) {
            const _Float16* kr = kb + (long)s0 * D_ + hoff;
            float4 kk0 = *(const float4*)kr;
            float4 kk1 = *(const float4*)(kr + 8);
            h2 kh[8];
            __builtin_memcpy(kh,     &kk0, 16);
            __builtin_memcpy(kh + 4, &kk1, 16);
            float dot = 0.f;
            #pragma unroll
            for (int i2 = 0; i2 < 8; ++i2) dot = dot2f(qv[i2], kh[i2], dot);
            d0 = dot * 0.125f;
        }
        if (s0 + 1 <= t) {
            const _Float16* kr = kb + (long)(s0 + 1) * D_ + hoff;
            float4 kk0 = *(const float4*)kr;
            float4 kk1 = *(const float4*)(kr + 8);
            h2 kh[8];
            __builtin_memcpy(kh,     &kk0, 16);
            __builtin_memcpy(kh + 4, &kk1, 16);
            float dot = 0.f;
            #pragma unroll
            for (int i2 = 0; i2 < 8; ++i2) dot = dot2f(qv[i2], kh[i2], dot);
            d1 = dot * 0.125f;
        }
        v[2*j] = d0; v[2*j+1] = d1;
    }

    const float tau = entmax_tau<2 * NJ>(v, lane);

    unsigned* __restrict__ wp = (unsigned*)srow;
    #pragma unroll
    for (int j = 0; j < NJ; ++j) {
        const float d0 = fmaxf(v[2*j]   - tau, 0.f);
        const float d1 = fmaxf(v[2*j+1] - tau, 0.f);
        wp[64 * j + lane] = pack2h(d0 * d0, d1 * d1);
    }
}

template <int NJ>
__device__ inline void head_pair(
    const _Float16* __restrict__ kb, const h2* __restrict__ qvA,
    const h2* __restrict__ qvB, unsigned short* __restrict__ scb,
    int wave, int lane, int t)
{
    head_score_newton<NJ>(kb, qvA, scb + (wave * 2 + 0) * SCP_, lane, t,
                          (wave * 2 + 0) * DK_);
    head_score_newton<NJ>(kb, qvB, scb + (wave * 2 + 1) * SCP_, lane, t,
                          (wave * 2 + 1) * DK_);
}

// =======================================================================
// Attention: one block (256 threads, 4 waves) per (b, t).
// BLOCK WIDTH = 256 IS MEASURED-OPTIMAL (R11: 512 regressed 80->92.5 µs).
// Wave w owns heads 2w,2w+1: scores computed straight into Newton
// registers (no score-LDS round trip; 2 barriers removed vs R14).
// blockIdx -> t DESCENDING; f16 LDS weights (26 KB -> 6 blocks/CU).
// NO min-waves clamp (R2: VGPR cap spilled v[] = 13x HBM traffic).
// =======================================================================
__global__ __launch_bounds__(256) void attn_kernel(
    const _Float16* __restrict__ q16, const _Float16* __restrict__ k16,
    const float* __restrict__ vcomb, const float* __restrict__ xin,
    float* __restrict__ xout,
    const float* __restrict__ Wo, const float* __restrict__ bo,
    const float* __restrict__ lng, const float* __restrict__ lnb,
    float* __restrict__ logs)
{
    __shared__ unsigned short scb[H_ * SCP_];   // 24.7 KB f16 weights
    __shared__ float red[64];
    __shared__ float o16[DK_];
    __shared__ float yrow[D_];
    __shared__ float stat[2];

    const int blk = blockIdx.x;
    const int t = TT_ - 1 - (blk >> 1);   // descending-work dispatch order
    const int b = blk & 1;
    const int tid = threadIdx.x;
    const int lane = tid & 63, wave = tid >> 6;
    const long rowq  = (long)b * TT_ + t;
    const long bbase = (long)b * TT_;

    // per-wave q for heads 2w, 2w+1 (uniform broadcast loads, no LDS)
    h2 qvA[8], qvB[8];
    {
        const h2* qp = (const h2*)(q16 + rowq * D_ + wave * 2 * DK_);
        #pragma unroll
        for (int i = 0; i < 8; ++i) { qvA[i] = qp[i]; qvB[i] = qp[8 + i]; }
    }

    // ---- fused score + entmax per head (registers only) ----
    {
        const _Float16* kb = k16 + bbase * D_;
        const int njn = (t >> 7) + 1;          // needed dwords: 1..12
        switch ((njn + 1) & ~1) {              // round up to even
        case 2:  head_pair<2 >(kb, qvA, qvB, scb, wave, lane, t); break;
        case 4:  head_pair<4 >(kb, qvA, qvB, scb, wave, lane, t); break;
        case 6:  head_pair<6 >(kb, qvA, qvB, scb, wave, lane, t); break;
        case 8:  head_pair<8 >(kb, qvA, qvB, scb, wave, lane, t); break;
        case 10: head_pair<10>(kb, qvA, qvB, scb, wave, lane, t); break;
        default: head_pair<12>(kb, qvA, qvB, scb, wave, lane, t); break;
        }
    }
    __syncthreads();

    // ---- w_avg via v_pk_add_f16 -> logs; acc16 += w_avg * v_comb ----
    float4 A0 = make_float4(0,0,0,0), A1 = A0, A2 = A0, A3 = A0;
    float* lrow = logs + rowq * TT_;
    const unsigned* __restrict__ rp0 = (const unsigned*)scb;
    #pragma unroll
    for (int it = 0; it < 3; ++it) {
        const int dwi = tid + 256 * it;       // 0..767
        const int s0 = 2 * dwi;
        if (s0 <= t) {
            h2 hs = __builtin_bit_cast(h2, rp0[dwi]);
            #pragma unroll
            for (int h = 1; h < H_; ++h)
                hs = hs + __builtin_bit_cast(h2, rp0[h * (SCP_ / 2) + dwi]);
            const float wa0 = (float)hs[0] * 0.125f;
            const float wa1 = (float)hs[1] * 0.125f;  // 0 beyond t
            {
                const float4* vp = (const float4*)(vcomb + (bbase + s0) * DK_);
                const float4 v0 = vp[0], v1 = vp[1], v2 = vp[2], v3 = vp[3];
                A0.x = fmaf(wa0, v0.x, A0.x); A0.y = fmaf(wa0, v0.y, A0.y);
                A0.z = fmaf(wa0, v0.z, A0.z); A0.w = fmaf(wa0, v0.w, A0.w);
                A1.x = fmaf(wa0, v1.x, A1.x); A1.y = fmaf(wa0, v1.y, A1.y);
                A1.z = fmaf(wa0, v1.z, A1.z); A1.w = fmaf(wa0, v1.w, A1.w);
                A2.x = fmaf(wa0, v2.x, A2.x); A2.y = fmaf(wa0, v2.y, A2.y);
                A2.z = fmaf(wa0, v2.z, A2.z); A2.w = fmaf(wa0, v2.w, A2.w);
                A3.x = fmaf(wa0, v3.x, A3.x); A3.y = fmaf(wa0, v3.y, A3.y);
                A3.z = fmaf(wa0, v3.z, A3.z); A3.w = fmaf(wa0, v3.w, A3.w);
            }
            if (s0 + 1 <= t) {
                const float4* vp = (const float4*)(vcomb + (bbase + s0 + 1) * DK_);
                const float4 v0 = vp[0], v1 = vp[1], v2 = vp[2], v3 = vp[3];
                A0.x = fmaf(wa1, v0.x, A0.x); A0.y = fmaf(wa1, v0.y, A0.y);
                A0.z = fmaf(wa1, v0.z, A0.z); A0.w = fmaf(wa1, v0.w, A0.w);
                A1.x = fmaf(wa1, v1.x, A1.x); A1.y = fmaf(wa1, v1.y, A1.y);
                A1.z = fmaf(wa1, v1.z, A1.z); A1.w = fmaf(wa1, v1.w, A1.w);
                A2.x = fmaf(wa1, v2.x, A2.x); A2.y = fmaf(wa1, v2.y, A2.y);
                A2.z = fmaf(wa1, v2.z, A2.z); A2.w = fmaf(wa1, v2.w, A2.w);
                A3.x = fmaf(wa1, v3.x, A3.x); A3.y = fmaf(wa1, v3.y, A3.y);
                A3.z = fmaf(wa1, v3.z, A3.z); A3.w = fmaf(wa1, v3.w, A3.w);
            }
            *(float2*)(lrow + s0) = make_float2(wa0, wa1);
        } else {
            *(float2*)(lrow + s0) = make_float2(0.f, 0.f);
        }
    }
    #pragma unroll
    for (int off = 32; off; off >>= 1) {
        A0.x += __shfl_xor(A0.x, off); A0.y += __shfl_xor(A0.y, off);
        A0.z += __shfl_xor(A0.z, off); A0.w += __shfl_xor(A0.w, off);
        A1.x += __shfl_xor(A1.x, off); A1.y += __shfl_xor(A1.y, off);
        A1.z += __shfl_xor(A1.z, off); A1.w += __shfl_xor(A1.w, off);
        A2.x += __shfl_xor(A2.x, off); A2.y += __shfl_xor(A2.y, off);
        A2.z += __shfl_xor(A2.z, off); A2.w += __shfl_xor(A2.w, off);
        A3.x += __shfl_xor(A3.x, off); A3.y += __shfl_xor(A3.y, off);
        A3.z += __shfl_xor(A3.z, off); A3.w += __shfl_xor(A3.w, off);
    }
    if (lane == 0) {
        float* r = red + wave * 16;
        r[0]=A0.x; r[1]=A0.y; r[2]=A0.z; r[3]=A0.w;
        r[4]=A1.x; r[5]=A1.y; r[6]=A1.z; r[7]=A1.w;
        r[8]=A2.x; r[9]=A2.y; r[10]=A2.z; r[11]=A2.w;
        r[12]=A3.x; r[13]=A3.y; r[14]=A3.z; r[15]=A3.w;
    }
    __syncthreads();
    if (tid < DK_) o16[tid] = red[tid] + red[16 + tid] + red[32 + tid] + red[48 + tid];
    __syncthreads();

    // ---- @Wo + bo, residual, LN1 (single-pass mean/var) ----
    float y = 0.f;
    if (tid < D_) {
        float a = bo[tid];
        #pragma unroll
        for (int j = 0; j < DK_; ++j) a = fmaf(o16[j], Wo[j * D_ + tid], a);
        y = xin[rowq * D_ + tid] + a;
        yrow[tid] = y;
    }
    __syncthreads();
    if (tid < 64) {
        const float y0 = yrow[tid], y1 = yrow[tid + 64];
        float sm = y0 + y1;
        float sq = fmaf(y0, y0, y1 * y1);
        #pragma unroll
        for (int off = 32; off; off >>= 1) {
            sm += __shfl_xor(sm, off);
            sq += __shfl_xor(sq, off);
        }
        if (tid == 0) {
            const float mean = sm * (1.0f / D_);
            stat[0] = mean;
            stat[1] = fmaxf(sq * (1.0f / D_) - mean * mean, 0.f);
        }
    }
    __syncthreads();
    if (tid < D_) {
        const float r = rsqrtf(stat[1] + 1e-5f);
        xout[rowq * D_ + tid] = (y - stat[0]) * r * lng[tid] + lnb[tid];
    }
}

// =======================================================================
// FFN + LN2 (+ fused next-layer QKV, or final projection).
// 4 rows per block (256 threads, 768 blocks = 3/CU). GEMM2 j-split +
// LDS partial reduce; single-pass LN.
// =======================================================================
__global__ __launch_bounds__(256) void ffn_kernel(
    const float* __restrict__ xin, float* __restrict__ xout,
    const float* __restrict__ fw1, const float* __restrict__ fb1,
    const float* __restrict__ fw2, const float* __restrict__ fb2,
    const float* __restrict__ g, const float* __restrict__ bta,
    int do_qkv,
    const float* __restrict__ Wq, const float* __restrict__ bq,
    const float* __restrict__ Wk, const float* __restrict__ bk,
    const float* __restrict__ wvc, const float* __restrict__ bvc,
    _Float16* __restrict__ q16, _Float16* __restrict__ k16,
    float* __restrict__ vc,
    int do_proj, const float* __restrict__ pw,
    const float* __restrict__ pb, float* __restrict__ outp)
{
    __shared__ float xrT[D_][4];     // [i][r]  2 KB (reused for normalized)
    __shared__ float hbT[DFF_][4];   // [j][r]  8 KB
    __shared__ float pred[2][4][D_]; //         4 KB (GEMM2 partials)
    __shared__ float yb[4][D_];      //         2 KB
    __shared__ float xn[D_];         // last-row normalized (proj) 0.5 KB

    const long row0 = (long)blockIdx.x * 4;
    const int tid = threadIdx.x;

    for (int idx = tid; idx < 4 * D_; idx += 256) {
        const int r = idx >> 7, i = idx & 127;
        xrT[i][r] = xin[row0 * D_ + idx];
    }
    __syncthreads();

    // GEMM1 + relu: thread owns cols c and c+256
    {
        const int c = tid;
        float4 a0 = make_float4(0,0,0,0), a1 = a0;
        for (int i = 0; i < D_; ++i) {
            const float w0 = fw1[i * DFF_ + c];
            const float w1 = fw1[i * DFF_ + c + 256];
            const float4 xv = *(const float4*)&xrT[i][0];
            a0.x = fmaf(xv.x, w0, a0.x); a0.y = fmaf(xv.y, w0, a0.y);
            a0.z = fmaf(xv.z, w0, a0.z); a0.w = fmaf(xv.w, w0, a0.w);
            a1.x = fmaf(xv.x, w1, a1.x); a1.y = fmaf(xv.y, w1, a1.y);
            a1.z = fmaf(xv.z, w1, a1.z); a1.w = fmaf(xv.w, w1, a1.w);
        }
        const float b0 = fb1[c], b1 = fb1[c + 256];
        float4 h0, h1;
        h0.x = fmaxf(a0.x + b0, 0.f); h0.y = fmaxf(a0.y + b0, 0.f);
        h0.z = fmaxf(a0.z + b0, 0.f); h0.w = fmaxf(a0.w + b0, 0.f);
        h1.x = fmaxf(a1.x + b1, 0.f); h1.y = fmaxf(a1.y + b1, 0.f);
        h1.z = fmaxf(a1.z + b1, 0.f); h1.w = fmaxf(a1.w + b1, 0.f);
        *(float4*)&hbT[c][0]       = h0;
        *(float4*)&hbT[c + 256][0] = h1;
    }
    __syncthreads();

    // GEMM2 partials: thread (d, half) does 4 rows over half the j range
    {
        const int d = tid & 127;
        const int half = tid >> 7;
        const int j0 = half * 256;
        float a0 = 0.f, a1 = 0.f, a2 = 0.f, a3 = 0.f;
        for (int j = j0; j < j0 + 256; ++j) {
            const float wv = fw2[j * D_ + d];
            const float4 hv = *(const float4*)&hbT[j][0];
            a0 = fmaf(hv.x, wv, a0);
            a1 = fmaf(hv.y, wv, a1);
            a2 = fmaf(hv.z, wv, a2);
            a3 = fmaf(hv.w, wv, a3);
        }
        pred[half][0][d] = a0; pred[half][1][d] = a1;
        pred[half][2][d] = a2; pred[half][3][d] = a3;
    }
    __syncthreads();

    // combine + bias + residual: thread owns (d, 2 rows)
    {
        const int d = tid & 127;
        const int r0 = (tid >> 7) * 2;
        const float bb = fb2[d];
        yb[r0 + 0][d] = pred[0][r0 + 0][d] + pred[1][r0 + 0][d] + bb + xrT[d][r0 + 0];
        yb[r0 + 1][d] = pred[0][r0 + 1][d] + pred[1][r0 + 1][d] + bb + xrT[d][r0 + 1];
    }
    __syncthreads();

    // LN per row (single-pass): wave w handles row w; normalized -> xrT
    const int w = tid >> 6, lane = tid & 63;
    const bool pblk = do_proj && (((row0 + 4) % TT_) == 0);
    {
        const float y0 = yb[w][lane], y1 = yb[w][lane + 64];
        float sm = y0 + y1;
        float sq = fmaf(y0, y0, y1 * y1);
        #pragma unroll
        for (int off = 32; off; off >>= 1) {
            sm += __shfl_xor(sm, off);
            sq += __shfl_xor(sq, off);
        }
        const float mean = sm * (1.0f / D_);
        const float var  = fmaxf(sq * (1.0f / D_) - mean * mean, 0.f);
        const float rcp = rsqrtf(var + 1e-5f);
        const float o0 = (y0 - mean) * rcp * g[lane]      + bta[lane];
        const float o1 = (y1 - mean) * rcp * g[lane + 64] + bta[lane + 64];
        xout[(row0 + w) * D_ + lane]      = o0;
        xout[(row0 + w) * D_ + lane + 64] = o1;
        xrT[lane][w]      = o0;           // re-stash for fused qkv
        xrT[lane + 64][w] = o1;
        if (pblk && w == 3) { xn[lane] = o0; xn[lane + 64] = o1; }
    }

    if (do_qkv) {
        __syncthreads();   // xrT now holds the 4 normalized rows
        const int c = tid & 127;
        const int which = tid >> 7;             // 0: q, 1: k (wave-uniform)
        const float* __restrict__ W = which ? Wk : Wq;
        const float bb = which ? bk[c] : bq[c];
        float a0 = bb, a1 = bb, a2 = bb, a3 = bb;
        for (int i = 0; i < D_; ++i) {
            const float wv = W[i * D_ + c];
            const float4 xv = *(const float4*)&xrT[i][0];
            a0 = fmaf(xv.x, wv, a0);
            a1 = fmaf(xv.y, wv, a1);
            a2 = fmaf(xv.z, wv, a2);
            a3 = fmaf(xv.w, wv, a3);
        }
        _Float16* __restrict__ dst = which ? k16 : q16;
        dst[(row0 + 0) * D_ + c] = (_Float16)a0;
        dst[(row0 + 1) * D_ + c] = (_Float16)a1;
        dst[(row0 + 2) * D_ + c] = (_Float16)a2;
        dst[(row0 + 3) * D_ + c] = (_Float16)a3;

        if (tid < 64) {
            const int r = tid >> 4, c16 = tid & 15;
            float av = bvc[c16];
            for (int i = 0; i < D_; ++i)
                av = fmaf(xrT[i][r], wvc[i * DK_ + c16], av);
            vc[(row0 + r) * DK_ + c16] = av;
        }
    }

    if (pblk) {
        __syncthreads();   // block-uniform condition — safe
        const int b = (int)((row0 + 3) / TT_);
        for (int idx = tid; idx < NQ_ * HOR_; idx += 256) {
            const int qq = idx / HOR_, hh = idx - qq * HOR_;
            float s = pb[idx];
            for (int d = 0; d < D_; ++d)
                s = fmaf(xn[d], pw[((long)qq * D_ + d) * HOR_ + hh], s);
            outp[b * NQ_ * HOR_ + idx] = s;
        }
    }
}

} // namespace

extern "C" void kernel_launch(void* const* d_in, const int* in_sizes, int n_in,
                              void* d_out, int out_size, void* d_ws, size_t ws_size,
                              hipStream_t stream) {
    (void)in_sizes; (void)n_in; (void)out_size; (void)ws_size;

    const float* x_cond = (const float*)d_in[0];
    const float* x_pred = (const float*)d_in[1];
    const float* cw_c   = (const float*)d_in[2];
    const float* cb_c   = (const float*)d_in[3];
    const float* sw_c   = (const float*)d_in[4];
    const float* sb_c   = (const float*)d_in[5];
    const float* cw_p   = (const float*)d_in[6];
    const float* cb_p   = (const float*)d_in[7];
    const float* sw_p   = (const float*)d_in[8];
    const float* sb_p   = (const float*)d_in[9];
    const float* Wq     = (const float*)d_in[10];
    const float* bq     = (const float*)d_in[11];
    const float* Wk     = (const float*)d_in[12];
    const float* bk     = (const float*)d_in[13];
    const float* Wv     = (const float*)d_in[14];
    const float* bv     = (const float*)d_in[15];
    const float* Wo     = (const float*)d_in[16];
    const float* bo     = (const float*)d_in[17];
    const float* ln1g   = (const float*)d_in[18];
    const float* ln1b   = (const float*)d_in[19];
    const float* fw1    = (const float*)d_in[20];
    const float* fb1    = (const float*)d_in[21];
    const float* fw2    = (const float*)d_in[22];
    const float* fb2    = (const float*)d_in[23];
    const float* ln2g   = (const float*)d_in[24];
    const float* ln2b   = (const float*)d_in[25];
    const float* pw     = (const float*)d_in[26];
    const float* pb     = (const float*)d_in[27];

    float* outp = (float*)d_out;
    float* ws   = (float*)d_ws;
    float*     xA   = ws + WS_XA;
    float*     xB   = ws + WS_XB;
    _Float16*  q16  = (_Float16*)(ws + WS_Q16);
    _Float16*  k16  = (_Float16*)(ws + WS_K16);
    float*     vcb  = ws + WS_VC;
    float*     wvc  = ws + WS_WVC;
    float*     bvc  = ws + WS_BVC;

    // Wv head-mean for both layers (tiny; must precede pre's fused QKV)
    prep_wvc_kernel<<<L_, 128, 0, stream>>>(Wv, bv, wvc, bvc);

    // selectors + layer-0 QKV, one launch
    pre_kernel<<<NB_ * TC_ + NB_ * TP_, 256, 0, stream>>>(
        x_cond, cw_c, cb_c, sw_c, sb_c,
        x_pred, cw_p, cb_p, sw_p, sb_p,
        outp + OFF_VC, outp + OFF_VP, xA,
        Wq, bq, Wk, bk, wvc, bvc, q16, k16, vcb);

    for (int l = 0; l < L_; ++l) {
        attn_kernel<<<NB_ * TT_, 256, 0, stream>>>(
            q16, k16, vcb, xA, xB,
            Wo + (long)l * DK_ * D_, bo + l * D_,
            ln1g + l * D_, ln1b + l * D_,
            outp + OFF_LOGS + (long)l * NB_ * TT_ * TT_);
        const int nl = l + 1;
        ffn_kernel<<<NB_ * TT_ / 4, 256, 0, stream>>>(
            xB, xA, fw1 + (long)l * D_ * DFF_, fb1 + l * DFF_,
            fw2 + (long)l * DFF_ * D_, fb2 + l * D_,
            ln2g + l * D_, ln2b + l * D_,
            (l < L_ - 1) ? 1 : 0,
            Wq + (long)nl * D_ * D_ * (l < L_ - 1),
            bq + nl * D_ * (l < L_ - 1),
            Wk + (long)nl * D_ * D_ * (l < L_ - 1),
            bk + nl * D_ * (l < L_ - 1),
            wvc + nl * D_ * DK_ * (l < L_ - 1),
            bvc + nl * DK_ * (l < L_ - 1),
            q16, k16, vcb,
            (l == L_ - 1) ? 1 : 0, pw, pb, outp);
    }
}

// Round 16
// 335.667 us; speedup vs baseline: 1.2496x; 1.2496x over previous
//
#include <hip/hip_runtime.h>

namespace {

constexpr int NB_  = 2;
constexpr int TC_  = 1024;
constexpr int TP_  = 512;
constexpr int TT_  = 1536;   // TC + TP
constexpr int D_   = 128;
constexpr int H_   = 8;
constexpr int DK_  = 16;
constexpr int DFF_ = 512;
constexpr int L_   = 2;
constexpr int HOR_ = 96;
constexpr int NQ_  = 3;

constexpr int SCP_ = TT_ + 8;   // ushort stride per head row (even → dword-tiled)

typedef _Float16 h2 __attribute__((ext_vector_type(2)));

// ---- output float offsets (return order: out, v_cond, v_pred, logs) ----
constexpr int OFF_OUT  = 0;
constexpr int OFF_VC   = NB_ * NQ_ * HOR_;            // 576
constexpr int OFF_VP   = OFF_VC + NB_ * TC_ * 8;      // 16960
constexpr int OFF_LOGS = OFF_VP + NB_ * TP_ * 4;      // 21056

// ---- workspace float offsets ----
constexpr int WS_XA  = 0;
constexpr int WS_XB  = WS_XA  + NB_ * TT_ * D_;       // 393216
constexpr int WS_Q16 = WS_XB  + NB_ * TT_ * D_;       // f16, half-sized
constexpr int WS_K16 = WS_Q16 + NB_ * TT_ * D_ / 2;
constexpr int WS_VC  = WS_K16 + NB_ * TT_ * D_ / 2;
constexpr int WS_WVC = WS_VC  + NB_ * TT_ * DK_;      // 2 layers x 2048
constexpr int WS_BVC = WS_WVC + L_ * D_ * DK_;        // 2 layers x 16

__device__ inline float dot2f(h2 a, h2 b, float c) {
#if __has_builtin(__builtin_amdgcn_fdot2)
    return __builtin_amdgcn_fdot2(a, b, c, false);
#else
    return c + (float)a[0] * (float)b[0] + (float)a[1] * (float)b[1];
#endif
}

__device__ inline unsigned pack2h(float a, float b) {   // 1 inst: v_cvt_pkrtz
#if __has_builtin(__builtin_amdgcn_cvt_pkrtz)
    return __builtin_bit_cast(unsigned, __builtin_amdgcn_cvt_pkrtz(a, b));
#else
    h2 p; p[0] = (_Float16)a; p[1] = (_Float16)b;
    return __builtin_bit_cast(unsigned, p);
#endif
}

// =======================================================================
// Wv head-mean prep (tiny separate launch so wvc/bvc are ready before
// pre_kernel's fused QKV — no intra-kernel block-ordering assumption).
// =======================================================================
__global__ __launch_bounds__(128) void prep_wvc_kernel(
    const float* __restrict__ Wv, const float* __restrict__ bv,
    float* __restrict__ wvc, float* __restrict__ bvc)
{
    const int l = blockIdx.x;
    const float* W  = Wv + (long)l * D_ * D_;
    const float* bb = bv + l * D_;
    float* wv = wvc + l * D_ * DK_;
    float* bo = bvc + l * DK_;
    const int tid = threadIdx.x;
    for (int idx = tid; idx < D_ * DK_; idx += 128) {
        const int i = idx >> 4, dk = idx & 15;
        float s = 0.f;
        #pragma unroll
        for (int hh = 0; hh < H_; ++hh) s += W[i * D_ + hh * DK_ + dk];
        wv[idx] = s * 0.125f;
    }
    if (tid < DK_) {
        float s = 0.f;
        #pragma unroll
        for (int hh = 0; hh < H_; ++hh) s += bb[hh * DK_ + tid];
        bo[tid] = s * 0.125f;
    }
}

// =======================================================================
// Selector + fused layer-0 QKV, 256 threads per (b, t).
// =======================================================================
template <int NV>
__device__ inline void selector_qkv_body(
    const float* __restrict__ x, const float* __restrict__ cw,
    const float* __restrict__ cb, const float* __restrict__ sw,
    const float* __restrict__ sb, float* __restrict__ vout,
    float* __restrict__ xout, int Tsel, int row_off, int blk,
    const float* __restrict__ Wq, const float* __restrict__ bq,
    const float* __restrict__ Wk, const float* __restrict__ bk,
    const float* __restrict__ wvc, const float* __restrict__ bvc,
    _Float16* __restrict__ q16, _Float16* __restrict__ k16,
    float* __restrict__ vc)
{
    const int b = blk / Tsel;
    const int t = blk - b * Tsel;
    const int tid = threadIdx.x;         // 0..255
    const int d = tid & 127;
    const int hi = tid >> 7;             // wave-uniform
    const int lane = tid & 63, wave = tid >> 6;

    __shared__ float wsum[4][NV];
    __shared__ float wls[NV];
    __shared__ float xr[D_];
    __shared__ float vred[DK_][8];

    float xw[3 * NV];
    #pragma unroll
    for (int kk = 0; kk < 3; ++kk) {
        const int ts = t + kk - 2;
        #pragma unroll
        for (int v = 0; v < NV; ++v)
            xw[kk * NV + v] = (ts >= 0) ? x[((long)b * Tsel + ts) * NV + v] : 0.0f;
    }

    float ls[NV];
    #pragma unroll
    for (int v = 0; v < NV; ++v) {
        const float* cwp = cw + ((long)(v * D_ + d)) * 3;
        float a = cb[v * D_ + d];
        a = fmaf(xw[0 * NV + v], cwp[0], a);
        a = fmaf(xw[1 * NV + v], cwp[1], a);
        a = fmaf(xw[2 * NV + v], cwp[2], a);
        ls[v] = a;
    }

    {
        const float swd = sw[d];
        float p[NV];
        #pragma unroll
        for (int v = 0; v < NV; ++v) p[v] = ls[v] * swd;
        #pragma unroll
        for (int off = 32; off; off >>= 1) {
            #pragma unroll
            for (int v = 0; v < NV; ++v) p[v] += __shfl_xor(p[v], off);
        }
        if (lane == 0) {
            #pragma unroll
            for (int v = 0; v < NV; ++v) wsum[wave][v] = p[v];
        }
    }
    __syncthreads();

    if (tid == 0) {   // waves 2,3 hold duplicates; use waves 0,1 only
        float u[NV];
        float m = -1e30f;
        #pragma unroll
        for (int v = 0; v < NV; ++v) {
            float s = wsum[0][v] + wsum[1][v] + sb[0];
            s = fminf(fmaxf(s, -10.0f), 10.0f);
            u[v] = 0.5f * s;
            m = fmaxf(m, u[v]);
        }
        float tau = m - 1.0f;
        for (int it = 0; it < 12; ++it) {
            float S1 = 0.f, S2 = 0.f;
            #pragma unroll
            for (int v = 0; v < NV; ++v) {
                float dd = fmaxf(u[v] - tau, 0.f);
                S1 += dd; S2 = fmaf(dd, dd, S2);
            }
            tau += (S2 - 1.0f) / (2.0f * S1);
        }
        {
            float S1 = 0.f, S2 = 0.f, K = 0.f;
            #pragma unroll
            for (int v = 0; v < NV; ++v) {
                if (u[v] > tau) { S1 += u[v]; S2 = fmaf(u[v], u[v], S2); K += 1.f; }
            }
            const float mean = S1 / K;
            const float arg  = fmaxf(fmaf(mean, mean, -(S2 - 1.0f) / K), 0.f);
            tau = mean - sqrtf(arg);
        }
        #pragma unroll
        for (int v = 0; v < NV; ++v) {
            float dd = fmaxf(u[v] - tau, 0.f);
            wls[v] = dd * dd;
        }
    }
    __syncthreads();

    float acc = 0.f;
    #pragma unroll
    for (int v = 0; v < NV; ++v) acc = fmaf(ls[v], wls[v], acc);
    const long row = (long)b * TT_ + row_off + t;
    if (hi == 0) {
        xout[row * D_ + d] = acc;
        xr[d] = acc;
    }
    if (tid < NV) vout[((long)b * Tsel + t) * NV + tid] = wls[tid];
    __syncthreads();

    // ---- fused layer-0 QKV: half-block q, half-block k ----
    {
        const float* __restrict__ W = hi ? Wk : Wq;
        float a = hi ? bk[d] : bq[d];
        for (int i = 0; i < D_; ++i) a = fmaf(xr[i], W[i * D_ + d], a);
        _Float16* __restrict__ dst = hi ? k16 : q16;
        dst[row * D_ + d] = (_Float16)a;
    }

    if (tid < 128) {
        const int dk = tid & 15, ch = tid >> 4;
        float p = 0.f;
        #pragma unroll
        for (int i = 0; i < 16; ++i)
            p = fmaf(xr[ch * 16 + i], wvc[(ch * 16 + i) * DK_ + dk], p);
        vred[dk][ch] = p;
    }
    __syncthreads();
    if (tid < DK_) {
        float s = bvc[tid];
        #pragma unroll
        for (int ch = 0; ch < 8; ++ch) s += vred[tid][ch];
        vc[row * DK_ + tid] = s;
    }
}

__global__ __launch_bounds__(256) void pre_kernel(
    const float* __restrict__ x_cond, const float* __restrict__ cw_c,
    const float* __restrict__ cb_c, const float* __restrict__ sw_c,
    const float* __restrict__ sb_c,
    const float* __restrict__ x_pred, const float* __restrict__ cw_p,
    const float* __restrict__ cb_p, const float* __restrict__ sw_p,
    const float* __restrict__ sb_p,
    float* __restrict__ vc_out, float* __restrict__ vp_out,
    float* __restrict__ xout,
    const float* __restrict__ Wq, const float* __restrict__ bq,
    const float* __restrict__ Wk, const float* __restrict__ bk,
    const float* __restrict__ wvc, const float* __restrict__ bvc,
    _Float16* __restrict__ q16, _Float16* __restrict__ k16,
    float* __restrict__ vc)
{
    const int blk = blockIdx.x;
    if (blk < NB_ * TC_) {
        selector_qkv_body<8>(x_cond, cw_c, cb_c, sw_c, sb_c, vc_out, xout,
                             TC_, 0, blk, Wq, bq, Wk, bk, wvc, bvc,
                             q16, k16, vc);
    } else {
        selector_qkv_body<4>(x_pred, cw_p, cb_p, sw_p, sb_p, vp_out, xout,
                             TP_, TC_, blk - NB_ * TC_,
                             Wq, bq, Wk, bk, wvc, bvc, q16, k16, vc);
    }
}

// =======================================================================
// entmax15 Newton over one head row held in registers. NJ = dwords/lane.
// Scores/weights in LDS are f16. Fixed 7 from-below iterations + exact
// closed-form tau over the support. Writeback via v_cvt_pkrtz. No tail
// zero-fill (w_avg reads only dwi <= t/2 < 64*NJ — dead stores).
// =======================================================================
template <int NJ>
__device__ inline void entmax_head(unsigned short* __restrict__ srow,
                                   int lane, int t)
{
    const unsigned* __restrict__ rp = (const unsigned*)srow;
    unsigned dw[NJ];
    #pragma unroll
    for (int j = 0; j < NJ; ++j) dw[j] = rp[64 * j + lane];
    float v[2 * NJ];
    #pragma unroll
    for (int j = 0; j < NJ; ++j) {
        const int s0 = 128 * j + 2 * lane;
        const h2 hv = __builtin_bit_cast(h2, dw[j]);
        v[2*j]   = (s0     <= t) ? (float)hv[0] : -1e30f;
        v[2*j+1] = (s0 + 1 <= t) ? (float)hv[1] : -1e30f;
    }

    float m = -1e30f;
    #pragma unroll
    for (int j = 0; j < 2 * NJ; ++j) m = fmaxf(m, v[j]);
    #pragma unroll
    for (int off = 32; off; off >>= 1) m = fmaxf(m, __shfl_xor(m, off));

    float tau = m - 1.0f;   // f(tau0) >= 0
    #pragma unroll
    for (int it = 0; it < 7; ++it) {
        float S1 = 0.f, S2 = 0.f;
        #pragma unroll
        for (int j = 0; j < 2 * NJ; ++j) {
            const float d0 = fmaxf(v[j] - tau, 0.f);
            S1 += d0; S2 = fmaf(d0, d0, S2);
        }
        #pragma unroll
        for (int off = 32; off; off >>= 1) {
            S1 += __shfl_xor(S1, off);
            S2 += __shfl_xor(S2, off);
        }
        tau += (S2 - 1.0f) / (2.0f * S1);
    }
    {
        float S1 = 0.f, S2 = 0.f, K = 0.f;
        #pragma unroll
        for (int j = 0; j < 2 * NJ; ++j) {
            if (v[j] > tau) { S1 += v[j]; S2 = fmaf(v[j], v[j], S2); K += 1.f; }
        }
        #pragma unroll
        for (int off = 32; off; off >>= 1) {
            S1 += __shfl_xor(S1, off);
            S2 += __shfl_xor(S2, off);
            K  += __shfl_xor(K,  off);
        }
        const float mean = S1 / K;
        const float arg  = fmaxf(fmaf(mean, mean, -(S2 - 1.0f) / K), 0.f);
        tau = mean - sqrtf(arg);
    }
    unsigned* __restrict__ wp = (unsigned*)srow;
    #pragma unroll
    for (int j = 0; j < NJ; ++j) {
        const float d0 = fmaxf(v[2*j]   - tau, 0.f);
        const float d1 = fmaxf(v[2*j+1] - tau, 0.f);
        wp[64 * j + lane] = pack2h(d0 * d0, d1 * d1);
    }
}

template <int NJ>
__device__ inline void entmax_pair(unsigned short* __restrict__ scb,
                                   int wave, int lane, int t)
{
    entmax_head<NJ>(scb + (wave * 2 + 0) * SCP_, lane, t);
    entmax_head<NJ>(scb + (wave * 2 + 1) * SCP_, lane, t);
}

// =======================================================================
// Attention: one block (256 threads, 4 waves) per (b, t).  [R14 config]
// BLOCK WIDTH = 256 IS MEASURED-OPTIMAL (R11: 512 regressed 80->92.5 µs).
// SCORE PHASE GOES THROUGH LDS ON PURPOSE: R15 fused scores into Newton
// registers via per-lane global K loads — uncoalesced (64 lanes x 128
// different K rows), VALUBusy 55->36%, dur 79->118 µs. The LDS round-trip
// is a cheap layout transpose; consecutive tids here read consecutive
// 16B chunks of the SAME K row (fully coalesced). Do not re-fuse.
// blockIdx -> t DESCENDING; f16 Q/K + v_dot2; f16 score LDS (26 KB ->
// 6 blocks/CU); register Newton with even-NJ templates; pk_add_f16 w_avg.
// NO min-waves clamp (R2: VGPR cap spilled v[] = 13x HBM traffic).
// =======================================================================
__global__ __launch_bounds__(256) void attn_kernel(
    const _Float16* __restrict__ q16, const _Float16* __restrict__ k16,
    const float* __restrict__ vcomb, const float* __restrict__ xin,
    float* __restrict__ xout,
    const float* __restrict__ Wo, const float* __restrict__ bo,
    const float* __restrict__ lng, const float* __restrict__ lnb,
    float* __restrict__ logs)
{
    __shared__ unsigned short scb[H_ * SCP_];   // 24.7 KB f16 scores/weights
    __shared__ _Float16 qrow16[D_];
    __shared__ float red[64];
    __shared__ float o16[DK_];
    __shared__ float yrow[D_];
    __shared__ float stat[2];

    const int blk = blockIdx.x;
    const int t = TT_ - 1 - (blk >> 1);   // descending-work dispatch order
    const int b = blk & 1;
    const int tid = threadIdx.x;
    const int lane = tid & 63, wave = tid >> 6;
    const long rowq  = (long)b * TT_ + t;
    const long bbase = (long)b * TT_;

    if (tid < 64)
        ((unsigned*)qrow16)[tid] = ((const unsigned*)(q16 + rowq * D_))[tid];
    __syncthreads();

    // ---- scores: u = (q.k / 4) / 2 = dot * 0.125, f16 dot2, stored f16 ----
    {
        const int h  = tid & 7;
        const int sl = tid >> 3;   // 0..31
        unsigned short* __restrict__ srow = scb + h * SCP_;
        h2 qv[8];
        __builtin_memcpy(qv, (const _Float16*)qrow16 + h * DK_, 32);
        for (int s = sl; s <= t; s += 32) {
            float4 kk0, kk1;
            {
                const float4* kp4 = (const float4*)(k16 + (bbase + s) * D_ + h * DK_);
                kk0 = kp4[0]; kk1 = kp4[1];
            }
            h2 kh[8];
            __builtin_memcpy(kh,     &kk0, 16);
            __builtin_memcpy(kh + 4, &kk1, 16);
            float dot = 0.f;
            #pragma unroll
            for (int i2 = 0; i2 < 8; ++i2) dot = dot2f(qv[i2], kh[i2], dot);
            const _Float16 sh = (_Float16)(dot * 0.125f);
            srow[s] = __builtin_bit_cast(unsigned short, sh);
        }
    }
    __syncthreads();

    // ---- entmax15: wave w = heads 2w, 2w+1; even-NJ templates ----
    {
        const int njn = (t >> 7) + 1;          // needed dwords: 1..12
        switch ((njn + 1) & ~1) {              // round up to even
        case 2:  entmax_pair<2 >(scb, wave, lane, t); break;
        case 4:  entmax_pair<4 >(scb, wave, lane, t); break;
        case 6:  entmax_pair<6 >(scb, wave, lane, t); break;
        case 8:  entmax_pair<8 >(scb, wave, lane, t); break;
        case 10: entmax_pair<10>(scb, wave, lane, t); break;
        default: entmax_pair<12>(scb, wave, lane, t); break;
        }
    }
    __syncthreads();

    // ---- w_avg via v_pk_add_f16 -> logs; acc16 += w_avg * v_comb ----
    float4 A0 = make_float4(0,0,0,0), A1 = A0, A2 = A0, A3 = A0;
    float* lrow = logs + rowq * TT_;
    const unsigned* __restrict__ rp0 = (const unsigned*)scb;
    #pragma unroll
    for (int it = 0; it < 3; ++it) {
        const int dwi = tid + 256 * it;       // 0..767
        const int s0 = 2 * dwi;
        if (s0 <= t) {
            h2 hs = __builtin_bit_cast(h2, rp0[dwi]);
            #pragma unroll
            for (int h = 1; h < H_; ++h)
                hs = hs + __builtin_bit_cast(h2, rp0[h * (SCP_ / 2) + dwi]);
            const float wa0 = (float)hs[0] * 0.125f;
            const float wa1 = (float)hs[1] * 0.125f;  // 0 beyond t
            {
                const float4* vp = (const float4*)(vcomb + (bbase + s0) * DK_);
                const float4 v0 = vp[0], v1 = vp[1], v2 = vp[2], v3 = vp[3];
                A0.x = fmaf(wa0, v0.x, A0.x); A0.y = fmaf(wa0, v0.y, A0.y);
                A0.z = fmaf(wa0, v0.z, A0.z); A0.w = fmaf(wa0, v0.w, A0.w);
                A1.x = fmaf(wa0, v1.x, A1.x); A1.y = fmaf(wa0, v1.y, A1.y);
                A1.z = fmaf(wa0, v1.z, A1.z); A1.w = fmaf(wa0, v1.w, A1.w);
                A2.x = fmaf(wa0, v2.x, A2.x); A2.y = fmaf(wa0, v2.y, A2.y);
                A2.z = fmaf(wa0, v2.z, A2.z); A2.w = fmaf(wa0, v2.w, A2.w);
                A3.x = fmaf(wa0, v3.x, A3.x); A3.y = fmaf(wa0, v3.y, A3.y);
                A3.z = fmaf(wa0, v3.z, A3.z); A3.w = fmaf(wa0, v3.w, A3.w);
            }
            if (s0 + 1 <= t) {
                const float4* vp = (const float4*)(vcomb + (bbase + s0 + 1) * DK_);
                const float4 v0 = vp[0], v1 = vp[1], v2 = vp[2], v3 = vp[3];
                A0.x = fmaf(wa1, v0.x, A0.x); A0.y = fmaf(wa1, v0.y, A0.y);
                A0.z = fmaf(wa1, v0.z, A0.z); A0.w = fmaf(wa1, v0.w, A0.w);
                A1.x = fmaf(wa1, v1.x, A1.x); A1.y = fmaf(wa1, v1.y, A1.y);
                A1.z = fmaf(wa1, v1.z, A1.z); A1.w = fmaf(wa1, v1.w, A1.w);
                A2.x = fmaf(wa1, v2.x, A2.x); A2.y = fmaf(wa1, v2.y, A2.y);
                A2.z = fmaf(wa1, v2.z, A2.z); A2.w = fmaf(wa1, v2.w, A2.w);
                A3.x = fmaf(wa1, v3.x, A3.x); A3.y = fmaf(wa1, v3.y, A3.y);
                A3.z = fmaf(wa1, v3.z, A3.z); A3.w = fmaf(wa1, v3.w, A3.w);
            }
            *(float2*)(lrow + s0) = make_float2(wa0, wa1);
        } else {
            *(float2*)(lrow + s0) = make_float2(0.f, 0.f);
        }
    }
    #pragma unroll
    for (int off = 32; off; off >>= 1) {
        A0.x += __shfl_xor(A0.x, off); A0.y += __shfl_xor(A0.y, off);
        A0.z += __shfl_xor(A0.z, off); A0.w += __shfl_xor(A0.w, off);
        A1.x += __shfl_xor(A1.x, off); A1.y += __shfl_xor(A1.y, off);
        A1.z += __shfl_xor(A1.z, off); A1.w += __shfl_xor(A1.w, off);
        A2.x += __shfl_xor(A2.x, off); A2.y += __shfl_xor(A2.y, off);
        A2.z += __shfl_xor(A2.z, off); A2.w += __shfl_xor(A2.w, off);
        A3.x += __shfl_xor(A3.x, off); A3.y += __shfl_xor(A3.y, off);
        A3.z += __shfl_xor(A3.z, off); A3.w += __shfl_xor(A3.w, off);
    }
    if (lane == 0) {
        float* r = red + wave * 16;
        r[0]=A0.x; r[1]=A0.y; r[2]=A0.z; r[3]=A0.w;
        r[4]=A1.x; r[5]=A1.y; r[6]=A1.z; r[7]=A1.w;
        r[8]=A2.x; r[9]=A2.y; r[10]=A2.z; r[11]=A2.w;
        r[12]=A3.x; r[13]=A3.y; r[14]=A3.z; r[15]=A3.w;
    }
    __syncthreads();
    if (tid < DK_) o16[tid] = red[tid] + red[16 + tid] + red[32 + tid] + red[48 + tid];
    __syncthreads();

    // ---- @Wo + bo, residual, LN1 (single-pass mean/var) ----
    float y = 0.f;
    if (tid < D_) {
        float a = bo[tid];
        #pragma unroll
        for (int j = 0; j < DK_; ++j) a = fmaf(o16[j], Wo[j * D_ + tid], a);
        y = xin[rowq * D_ + tid] + a;
        yrow[tid] = y;
    }
    __syncthreads();
    if (tid < 64) {
        const float y0 = yrow[tid], y1 = yrow[tid + 64];
        float sm = y0 + y1;
        float sq = fmaf(y0, y0, y1 * y1);
        #pragma unroll
        for (int off = 32; off; off >>= 1) {
            sm += __shfl_xor(sm, off);
            sq += __shfl_xor(sq, off);
        }
        if (tid == 0) {
            const float mean = sm * (1.0f / D_);
            stat[0] = mean;
            stat[1] = fmaxf(sq * (1.0f / D_) - mean * mean, 0.f);
        }
    }
    __syncthreads();
    if (tid < D_) {
        const float r = rsqrtf(stat[1] + 1e-5f);
        xout[rowq * D_ + tid] = (y - stat[0]) * r * lng[tid] + lnb[tid];
    }
}

// =======================================================================
// FFN + LN2 (+ fused next-layer QKV, or final projection).
// 4 rows per block (256 threads, 768 blocks = 3/CU). GEMM2 j-split +
// LDS partial reduce; single-pass LN.
// =======================================================================
__global__ __launch_bounds__(256) void ffn_kernel(
    const float* __restrict__ xin, float* __restrict__ xout,
    const float* __restrict__ fw1, const float* __restrict__ fb1,
    const float* __restrict__ fw2, const float* __restrict__ fb2,
    const float* __restrict__ g, const float* __restrict__ bta,
    int do_qkv,
    const float* __restrict__ Wq, const float* __restrict__ bq,
    const float* __restrict__ Wk, const float* __restrict__ bk,
    const float* __restrict__ wvc, const float* __restrict__ bvc,
    _Float16* __restrict__ q16, _Float16* __restrict__ k16,
    float* __restrict__ vc,
    int do_proj, const float* __restrict__ pw,
    const float* __restrict__ pb, float* __restrict__ outp)
{
    __shared__ float xrT[D_][4];     // [i][r]  2 KB (reused for normalized)
    __shared__ float hbT[DFF_][4];   // [j][r]  8 KB
    __shared__ float pred[2][4][D_]; //         4 KB (GEMM2 partials)
    __shared__ float yb[4][D_];      //         2 KB
    __shared__ float xn[D_];         // last-row normalized (proj) 0.5 KB

    const long row0 = (long)blockIdx.x * 4;
    const int tid = threadIdx.x;

    for (int idx = tid; idx < 4 * D_; idx += 256) {
        const int r = idx >> 7, i = idx & 127;
        xrT[i][r] = xin[row0 * D_ + idx];
    }
    __syncthreads();

    // GEMM1 + relu: thread owns cols c and c+256
    {
        const int c = tid;
        float4 a0 = make_float4(0,0,0,0), a1 = a0;
        for (int i = 0; i < D_; ++i) {
            const float w0 = fw1[i * DFF_ + c];
            const float w1 = fw1[i * DFF_ + c + 256];
            const float4 xv = *(const float4*)&xrT[i][0];
            a0.x = fmaf(xv.x, w0, a0.x); a0.y = fmaf(xv.y, w0, a0.y);
            a0.z = fmaf(xv.z, w0, a0.z); a0.w = fmaf(xv.w, w0, a0.w);
            a1.x = fmaf(xv.x, w1, a1.x); a1.y = fmaf(xv.y, w1, a1.y);
            a1.z = fmaf(xv.z, w1, a1.z); a1.w = fmaf(xv.w, w1, a1.w);
        }
        const float b0 = fb1[c], b1 = fb1[c + 256];
        float4 h0, h1;
        h0.x = fmaxf(a0.x + b0, 0.f); h0.y = fmaxf(a0.y + b0, 0.f);
        h0.z = fmaxf(a0.z + b0, 0.f); h0.w = fmaxf(a0.w + b0, 0.f);
        h1.x = fmaxf(a1.x + b1, 0.f); h1.y = fmaxf(a1.y + b1, 0.f);
        h1.z = fmaxf(a1.z + b1, 0.f); h1.w = fmaxf(a1.w + b1, 0.f);
        *(float4*)&hbT[c][0]       = h0;
        *(float4*)&hbT[c + 256][0] = h1;
    }
    __syncthreads();

    // GEMM2 partials: thread (d, half) does 4 rows over half the j range
    {
        const int d = tid & 127;
        const int half = tid >> 7;
        const int j0 = half * 256;
        float a0 = 0.f, a1 = 0.f, a2 = 0.f, a3 = 0.f;
        for (int j = j0; j < j0 + 256; ++j) {
            const float wv = fw2[j * D_ + d];
            const float4 hv = *(const float4*)&hbT[j][0];
            a0 = fmaf(hv.x, wv, a0);
            a1 = fmaf(hv.y, wv, a1);
            a2 = fmaf(hv.z, wv, a2);
            a3 = fmaf(hv.w, wv, a3);
        }
        pred[half][0][d] = a0; pred[half][1][d] = a1;
        pred[half][2][d] = a2; pred[half][3][d] = a3;
    }
    __syncthreads();

    // combine + bias + residual: thread owns (d, 2 rows)
    {
        const int d = tid & 127;
        const int r0 = (tid >> 7) * 2;
        const float bb = fb2[d];
        yb[r0 + 0][d] = pred[0][r0 + 0][d] + pred[1][r0 + 0][d] + bb + xrT[d][r0 + 0];
        yb[r0 + 1][d] = pred[0][r0 + 1][d] + pred[1][r0 + 1][d] + bb + xrT[d][r0 + 1];
    }
    __syncthreads();

    // LN per row (single-pass): wave w handles row w; normalized -> xrT
    const int w = tid >> 6, lane = tid & 63;
    const bool pblk = do_proj && (((row0 + 4) % TT_) == 0);
    {
        const float y0 = yb[w][lane], y1 = yb[w][lane + 64];
        float sm = y0 + y1;
        float sq = fmaf(y0, y0, y1 * y1);
        #pragma unroll
        for (int off = 32; off; off >>= 1) {
            sm += __shfl_xor(sm, off);
            sq += __shfl_xor(sq, off);
        }
        const float mean = sm * (1.0f / D_);
        const float var  = fmaxf(sq * (1.0f / D_) - mean * mean, 0.f);
        const float rcp = rsqrtf(var + 1e-5f);
        const float o0 = (y0 - mean) * rcp * g[lane]      + bta[lane];
        const float o1 = (y1 - mean) * rcp * g[lane + 64] + bta[lane + 64];
        xout[(row0 + w) * D_ + lane]      = o0;
        xout[(row0 + w) * D_ + lane + 64] = o1;
        xrT[lane][w]      = o0;           // re-stash for fused qkv
        xrT[lane + 64][w] = o1;
        if (pblk && w == 3) { xn[lane] = o0; xn[lane + 64] = o1; }
    }

    if (do_qkv) {
        __syncthreads();   // xrT now holds the 4 normalized rows
        const int c = tid & 127;
        const int which = tid >> 7;             // 0: q, 1: k (wave-uniform)
        const float* __restrict__ W = which ? Wk : Wq;
        const float bb = which ? bk[c] : bq[c];
        float a0 = bb, a1 = bb, a2 = bb, a3 = bb;
        for (int i = 0; i < D_; ++i) {
            const float wv = W[i * D_ + c];
            const float4 xv = *(const float4*)&xrT[i][0];
            a0 = fmaf(xv.x, wv, a0);
            a1 = fmaf(xv.y, wv, a1);
            a2 = fmaf(xv.z, wv, a2);
            a3 = fmaf(xv.w, wv, a3);
        }
        _Float16* __restrict__ dst = which ? k16 : q16;
        dst[(row0 + 0) * D_ + c] = (_Float16)a0;
        dst[(row0 + 1) * D_ + c] = (_Float16)a1;
        dst[(row0 + 2) * D_ + c] = (_Float16)a2;
        dst[(row0 + 3) * D_ + c] = (_Float16)a3;

        if (tid < 64) {
            const int r = tid >> 4, c16 = tid & 15;
            float av = bvc[c16];
            for (int i = 0; i < D_; ++i)
                av = fmaf(xrT[i][r], wvc[i * DK_ + c16], av);
            vc[(row0 + r) * DK_ + c16] = av;
        }
    }

    if (pblk) {
        __syncthreads();   // block-uniform condition — safe
        const int b = (int)((row0 + 3) / TT_);
        for (int idx = tid; idx < NQ_ * HOR_; idx += 256) {
            const int qq = idx / HOR_, hh = idx - qq * HOR_;
            float s = pb[idx];
            for (int d = 0; d < D_; ++d)
                s = fmaf(xn[d], pw[((long)qq * D_ + d) * HOR_ + hh], s);
            outp[b * NQ_ * HOR_ + idx] = s;
        }
    }
}

} // namespace

extern "C" void kernel_launch(void* const* d_in, const int* in_sizes, int n_in,
                              void* d_out, int out_size, void* d_ws, size_t ws_size,
                              hipStream_t stream) {
    (void)in_sizes; (void)n_in; (void)out_size; (void)ws_size;

    const float* x_cond = (const float*)d_in[0];
    const float* x_pred = (const float*)d_in[1];
    const float* cw_c   = (const float*)d_in[2];
    const float* cb_c   = (const float*)d_in[3];
    const float* sw_c   = (const float*)d_in[4];
    const float* sb_c   = (const float*)d_in[5];
    const float* cw_p   = (const float*)d_in[6];
    const float* cb_p   = (const float*)d_in[7];
    const float* sw_p   = (const float*)d_in[8];
    const float* sb_p   = (const float*)d_in[9];
    const float* Wq     = (const float*)d_in[10];
    const float* bq     = (const float*)d_in[11];
    const float* Wk     = (const float*)d_in[12];
    const float* bk     = (const float*)d_in[13];
    const float* Wv     = (const float*)d_in[14];
    const float* bv     = (const float*)d_in[15];
    const float* Wo     = (const float*)d_in[16];
    const float* bo     = (const float*)d_in[17];
    const float* ln1g   = (const float*)d_in[18];
    const float* ln1b   = (const float*)d_in[19];
    const float* fw1    = (const float*)d_in[20];
    const float* fb1    = (const float*)d_in[21];
    const float* fw2    = (const float*)d_in[22];
    const float* fb2    = (const float*)d_in[23];
    const float* ln2g   = (const float*)d_in[24];
    const float* ln2b   = (const float*)d_in[25];
    const float* pw     = (const float*)d_in[26];
    const float* pb     = (const float*)d_in[27];

    float* outp = (float*)d_out;
    float* ws   = (float*)d_ws;
    float*     xA   = ws + WS_XA;
    float*     xB   = ws + WS_XB;
    _Float16*  q16  = (_Float16*)(ws + WS_Q16);
    _Float16*  k16  = (_Float16*)(ws + WS_K16);
    float*     vcb  = ws + WS_VC;
    float*     wvc  = ws + WS_WVC;
    float*     bvc  = ws + WS_BVC;

    // Wv head-mean for both layers (tiny; must precede pre's fused QKV)
    prep_wvc_kernel<<<L_, 128, 0, stream>>>(Wv, bv, wvc, bvc);

    // selectors + layer-0 QKV, one launch
    pre_kernel<<<NB_ * TC_ + NB_ * TP_, 256, 0, stream>>>(
        x_cond, cw_c, cb_c, sw_c, sb_c,
        x_pred, cw_p, cb_p, sw_p, sb_p,
        outp + OFF_VC, outp + OFF_VP, xA,
        Wq, bq, Wk, bk, wvc, bvc, q16, k16, vcb);

    for (int l = 0; l < L_; ++l) {
        attn_kernel<<<NB_ * TT_, 256, 0, stream>>>(
            q16, k16, vcb, xA, xB,
            Wo + (long)l * DK_ * D_, bo + l * D_,
            ln1g + l * D_, ln1b + l * D_,
            outp + OFF_LOGS + (long)l * NB_ * TT_ * TT_);
        const int nl = l + 1;
        ffn_kernel<<<NB_ * TT_ / 4, 256, 0, stream>>>(
            xB, xA, fw1 + (long)l * D_ * DFF_, fb1 + l * DFF_,
            fw2 + (long)l * DFF_ * D_, fb2 + l * D_,
            ln2g + l * D_, ln2b + l * D_,
            (l < L_ - 1) ? 1 : 0,
            Wq + (long)nl * D_ * D_ * (l < L_ - 1),
            bq + nl * D_ * (l < L_ - 1),
            Wk + (long)nl * D_ * D_ * (l < L_ - 1),
            bk + nl * D_ * (l < L_ - 1),
            wvc + nl * D_ * DK_ * (l < L_ - 1),
            bvc + nl * DK_ * (l < L_ - 1),
            q16, k16, vcb,
            (l == L_ - 1) ? 1 : 0, pw, pb, outp);
    }
}